// Round 12
// baseline (706.188 us; speedup 1.0000x reference)
//
#include <hip/hip_runtime.h>
#include <math.h>

#define BATCH 4
#define NQ 2048
#define NK 2048
#define DQ 1024
#define NHEADS 8
#define DHEAD 64
#define INNER (NHEADS*DHEAD)     // 512
#define NROWS (BATCH*NHEADS*NQ)  // 65536
#define CAND_MAX 128

using frag_ab = __attribute__((ext_vector_type(8))) short;   // 8 bf16
using frag_cd = __attribute__((ext_vector_type(4))) float;   // 4 fp32
using u16x8   = __attribute__((ext_vector_type(8))) unsigned short;

static __device__ __forceinline__ unsigned short f32_to_bf16_rne(float f) {
  unsigned u = __float_as_uint(f);
  u += 0x7FFFu + ((u >> 16) & 1u);
  return (unsigned short)(u >> 16);
}

// 2-way trunc split (for smooth-path mfma3): f ~ hi + lo, err ~2^-17|f|
static __device__ __forceinline__ void split_trunc(float f, unsigned short& h, unsigned short& l) {
  unsigned u = __float_as_uint(f);
  h = (unsigned short)(u >> 16);
  float hf = __uint_as_float(u & 0xFFFF0000u);
  unsigned r = __float_as_uint(f - hf);
  l = (unsigned short)(r >> 16);
}

// 3-way trunc split: f = hi + mid + lo EXACTLY (8+8+8 mantissa bits)
static __device__ __forceinline__ void split3(float f, unsigned short& h,
                                              unsigned short& m, unsigned short& l) {
  unsigned u = __float_as_uint(f);
  h = (unsigned short)(u >> 16);
  float hf = __uint_as_float(u & 0xFFFF0000u);
  float r1 = f - hf;                       // exact
  unsigned u1 = __float_as_uint(r1);
  m = (unsigned short)(u1 >> 16);
  float mf = __uint_as_float(u1 & 0xFFFF0000u);
  float r2 = r1 - mf;                      // exact, <=8 mantissa bits
  l = (unsigned short)(__float_as_uint(r2) >> 16);
}

// ---------------------------------------------------------------------------
// Weight transpose + 3-way split: W[K][ldw] (coloff) -> TH/TM/TL [N][K] u16.
// ---------------------------------------------------------------------------
__global__ __launch_bounds__(256) void split_wT3(
    const float* __restrict__ W, int ldw, int coloff, int K, int N,
    unsigned short* __restrict__ TH, unsigned short* __restrict__ TM,
    unsigned short* __restrict__ TL)
{
  __shared__ float tile[32*33];
  const int k0 = blockIdx.x * 32, n0 = blockIdx.y * 32;
  const int t = threadIdx.x;
  {
    int lk = t >> 3, ln4 = (t & 7) * 4;
    const float4 v = *(const float4*)(W + (size_t)(k0 + lk)*ldw + coloff + n0 + ln4);
    tile[lk*33 + ln4+0] = v.x;
    tile[lk*33 + ln4+1] = v.y;
    tile[lk*33 + ln4+2] = v.z;
    tile[lk*33 + ln4+3] = v.w;
  }
  __syncthreads();
  int n = t >> 3, k4 = (t & 7) * 4;
  #pragma unroll
  for (int j = 0; j < 4; ++j) {
    unsigned short h, m, l;
    split3(tile[(k4+j)*33 + n], h, m, l);
    size_t o = (size_t)(n0 + n)*K + k0 + k4 + j;
    TH[o] = h; TM[o] = m; TL[o] = l;
  }
}

// ---------------------------------------------------------------------------
// Weight transpose + 2-way split (smooth path).
// ---------------------------------------------------------------------------
__global__ __launch_bounds__(256) void split_wT(
    const float* __restrict__ W, int ldw, int coloff, int K, int N,
    unsigned short* __restrict__ TH, unsigned short* __restrict__ TL)
{
  __shared__ float tile[32*33];
  const int k0 = blockIdx.x * 32, n0 = blockIdx.y * 32;
  const int t = threadIdx.x;
  {
    int lk = t >> 3, ln4 = (t & 7) * 4;
    const float4 v = *(const float4*)(W + (size_t)(k0 + lk)*ldw + coloff + n0 + ln4);
    tile[lk*33 + ln4+0] = v.x;
    tile[lk*33 + ln4+1] = v.y;
    tile[lk*33 + ln4+2] = v.z;
    tile[lk*33 + ln4+3] = v.w;
  }
  __syncthreads();
  int n = t >> 3, k4 = (t & 7) * 4;
  #pragma unroll
  for (int j = 0; j < 4; ++j) {
    unsigned short h, l;
    split_trunc(tile[(k4+j)*33 + n], h, l);
    TH[(size_t)(n0 + n)*K + k0 + k4 + j] = h;
    TL[(size_t)(n0 + n)*K + k0 + k4 + j] = l;
  }
}

// ---------------------------------------------------------------------------
// 6-product bf16 MFMA projection GEMM (selection path, ~1e-6 abs err):
// MERGED x+ctx launch. Tile 128m x 128n, BK=32, 8 waves (512 thr),
// 61,440 B LDS -> 2 blocks/CU, grid 512 = exact fill.
// ---------------------------------------------------------------------------
__global__ __launch_bounds__(512) void gemm_mfma6_proj(
    const float* __restrict__ A0,
    const unsigned short* __restrict__ BtH0, const unsigned short* __restrict__ BtM0,
    const unsigned short* __restrict__ BtL0,
    float* __restrict__ C0_, unsigned short* __restrict__ Hi0, unsigned short* __restrict__ Lo0,
    const float* __restrict__ A1,
    const unsigned short* __restrict__ BtH1, const unsigned short* __restrict__ BtM1,
    const unsigned short* __restrict__ BtL1,
    float* __restrict__ C1_, unsigned short* __restrict__ Hi1, unsigned short* __restrict__ Lo1)
{
  extern __shared__ unsigned short smp[];
  unsigned short* ah = smp;            // [128][40] u16 each (rows 16B-aligned)
  unsigned short* am = ah + 128*40;
  unsigned short* al = am + 128*40;
  unsigned short* bh = al + 128*40;    // [128][40]
  unsigned short* bm = bh + 128*40;
  unsigned short* bl = bm + 128*40;    // total 61,440 B

  const int t = threadIdx.x;
  const int w = t >> 6, l = t & 63;
  const int lr = l & 15, quad = l >> 4;
  const int bid = (int)blockIdx.x;                  // grid 512
  const int half = bid >> 8;                        // 0: x-proj, 1: ctx-proj
  const int b2 = bid & 255;
  const int lid = (b2 & 7) * 32 + (b2 >> 3);        // per-half XCD chunking
  const int n0 = (lid & 3) * 128, m0 = (lid >> 2) * 128;

  const float* A = half ? A1 : A0;
  const unsigned short* BtH = half ? BtH1 : BtH0;
  const unsigned short* BtM = half ? BtM1 : BtM0;
  const unsigned short* BtL = half ? BtL1 : BtL0;
  float* C32 = half ? C1_ : C0_;
  unsigned short* Hi = half ? Hi1 : Hi0;
  unsigned short* Lo = half ? Lo1 : Lo0;

  frag_cd acc[8];
  #pragma unroll
  for (int nt = 0; nt < 8; ++nt)
    acc[nt] = (frag_cd){0.f, 0.f, 0.f, 0.f};

  for (int kt = 0; kt < DQ; kt += 32) {
    // stage A: 128x32 f32 -> 3-way split (one u16x8 triple per thread)
    {
      int row = t >> 2, k8 = (t & 3) * 8;
      const float* src = A + (size_t)(m0 + row) * DQ + kt + k8;
      float4 v0 = *(const float4*)(src);
      float4 v1 = *(const float4*)(src + 4);
      float vv[8] = {v0.x, v0.y, v0.z, v0.w, v1.x, v1.y, v1.z, v1.w};
      unsigned short h8[8], m8[8], l8[8];
      #pragma unroll
      for (int j = 0; j < 8; ++j) split3(vv[j], h8[j], m8[j], l8[j]);
      *(u16x8*)(ah + row*40 + k8) = *(u16x8*)h8;
      *(u16x8*)(am + row*40 + k8) = *(u16x8*)m8;
      *(u16x8*)(al + row*40 + k8) = *(u16x8*)l8;
    }
    // stage B: 128x32 pre-split copies (one u16x8 triple per thread)
    {
      int n = t >> 2, k8 = (t & 3) * 8;
      size_t o = (size_t)(n0 + n)*DQ + kt + k8;
      *(u16x8*)(bh + n*40 + k8) = *(const u16x8*)(BtH + o);
      *(u16x8*)(bm + n*40 + k8) = *(const u16x8*)(BtM + o);
      *(u16x8*)(bl + n*40 + k8) = *(const u16x8*)(BtL + o);
    }
    __syncthreads();
    {
      int row = w*16 + lr;
      frag_ab aH = *(const frag_ab*)(ah + row*40 + quad*8);
      frag_ab aM = *(const frag_ab*)(am + row*40 + quad*8);
      frag_ab aL = *(const frag_ab*)(al + row*40 + quad*8);
      #pragma unroll
      for (int nt = 0; nt < 8; ++nt) {
        int bn = nt*16 + lr;
        frag_ab bH_ = *(const frag_ab*)(bh + bn*40 + quad*8);
        frag_ab bM_ = *(const frag_ab*)(bm + bn*40 + quad*8);
        frag_ab bL_ = *(const frag_ab*)(bl + bn*40 + quad*8);
        frag_cd c = acc[nt];
        // small terms first to reduce rounding (order preserved)
        c = __builtin_amdgcn_mfma_f32_16x16x32_bf16(aL, bH_, c, 0, 0, 0);
        c = __builtin_amdgcn_mfma_f32_16x16x32_bf16(aH, bL_, c, 0, 0, 0);
        c = __builtin_amdgcn_mfma_f32_16x16x32_bf16(aM, bM_, c, 0, 0, 0);
        c = __builtin_amdgcn_mfma_f32_16x16x32_bf16(aM, bH_, c, 0, 0, 0);
        c = __builtin_amdgcn_mfma_f32_16x16x32_bf16(aH, bM_, c, 0, 0, 0);
        c = __builtin_amdgcn_mfma_f32_16x16x32_bf16(aH, bH_, c, 0, 0, 0);
        acc[nt] = c;
      }
    }
    __syncthreads();
  }

  #pragma unroll
  for (int nt = 0; nt < 8; ++nt) {
    int cc = n0 + nt*16 + lr;
    int h = cc >> 6, d = cc & 63;
    #pragma unroll
    for (int i = 0; i < 4; ++i) {
      int r = m0 + w*16 + quad*4 + i;
      int b = r >> 11, n = r & (NQ - 1);
      size_t idx = (((size_t)(b*NHEADS + h))*NQ + n)*64 + d;
      float vf = acc[nt][i];
      C32[idx] = vf;
      unsigned short hb = f32_to_bf16_rne(vf);
      float hf = __uint_as_float((unsigned)hb << 16);
      unsigned short lb = f32_to_bf16_rne(vf - hf);
      Hi[idx] = hb;
      Lo[idx] = lb;
    }
  }
}

// ---------------------------------------------------------------------------
// bf16x3 MFMA GEMM (smooth path). Tile 128m x 128n, BK=32, 8 waves (512 thr),
// 40,960 B LDS. 1D grid + chunked XCD swizzle.
// MODE 0: +bias row-major; MODE 2: scatter V[bh][n][d].
// ---------------------------------------------------------------------------
template<int MODE>
__global__ __launch_bounds__(512) void gemm_mfma3(
    const float* __restrict__ A, int lda,
    const unsigned short* __restrict__ BtH, const unsigned short* __restrict__ BtL,
    int K, int N, const float* __restrict__ bias, float* __restrict__ C0)
{
  __shared__ unsigned short ah[128*40];
  __shared__ unsigned short al[128*40];
  __shared__ unsigned short bh2[128*40];
  __shared__ unsigned short bl2[128*40];   // total 40,960 B
  const int t = threadIdx.x;
  const int w = t >> 6, l = t & 63;
  const int lr = l & 15, quad = l >> 4;
  const int nx = N >> 7;                       // 128-col n-blocks
  const int bid = (int)blockIdx.x;
  const int nwg = (int)gridDim.x;              // %8 == 0
  const int lid = (bid & 7) * (nwg >> 3) + (bid >> 3);
  const int n0 = (lid % nx) * 128, m0 = (lid / nx) * 128;

  frag_cd acc[8];
  #pragma unroll
  for (int nt = 0; nt < 8; ++nt)
    acc[nt] = (frag_cd){0.f, 0.f, 0.f, 0.f};

  for (int kt = 0; kt < K; kt += 32) {
    // stage A: 128x32 f32 -> 2-way split (one u16x8 pair per thread)
    {
      int row = t >> 2, k8 = (t & 3) * 8;
      const float* src = A + (size_t)(m0 + row) * lda + kt + k8;
      float4 v0 = *(const float4*)(src);
      float4 v1 = *(const float4*)(src + 4);
      float vv[8] = {v0.x, v0.y, v0.z, v0.w, v1.x, v1.y, v1.z, v1.w};
      unsigned short h8[8], l8[8];
      #pragma unroll
      for (int j = 0; j < 8; ++j) split_trunc(vv[j], h8[j], l8[j]);
      *(u16x8*)(ah + row*40 + k8) = *(u16x8*)h8;
      *(u16x8*)(al + row*40 + k8) = *(u16x8*)l8;
    }
    // stage B: 128x32 pre-split copies (one u16x8 pair per thread)
    {
      int n = t >> 2, k8 = (t & 3) * 8;
      size_t o = (size_t)(n0 + n)*K + kt + k8;
      *(u16x8*)(bh2 + n*40 + k8) = *(const u16x8*)(BtH + o);
      *(u16x8*)(bl2 + n*40 + k8) = *(const u16x8*)(BtL + o);
    }
    __syncthreads();
    {
      int row = w*16 + lr;
      frag_ab aH = *(const frag_ab*)(ah + row*40 + quad*8);
      frag_ab aL = *(const frag_ab*)(al + row*40 + quad*8);
      #pragma unroll
      for (int nt = 0; nt < 8; ++nt) {
        int bn = nt*16 + lr;
        frag_ab bH_ = *(const frag_ab*)(bh2 + bn*40 + quad*8);
        frag_ab bL_ = *(const frag_ab*)(bl2 + bn*40 + quad*8);
        acc[nt] = __builtin_amdgcn_mfma_f32_16x16x32_bf16(aH, bH_, acc[nt], 0, 0, 0);
        acc[nt] = __builtin_amdgcn_mfma_f32_16x16x32_bf16(aH, bL_, acc[nt], 0, 0, 0);
        acc[nt] = __builtin_amdgcn_mfma_f32_16x16x32_bf16(aL, bH_, acc[nt], 0, 0, 0);
      }
    }
    __syncthreads();
  }

  #pragma unroll
  for (int nt = 0; nt < 8; ++nt) {
    int cc = n0 + nt*16 + lr;
    #pragma unroll
    for (int i = 0; i < 4; ++i) {
      int r = m0 + w*16 + quad*4 + i;
      float v = acc[nt][i];
      if (MODE == 0) {
        C0[(size_t)r * N + cc] = v + bias[cc];
      } else {
        int b = r >> 11, n = r & (NQ - 1);
        int h = cc >> 6, d = cc & 63;
        C0[(((size_t)(b*NHEADS + h))*NK + n)*64 + d] = v;
      }
    }
  }
}

// ---------------------------------------------------------------------------
// Score GEMM via bf16x3 MFMA -> f16 scores. 512 threads (8 waves, one 16-row
// q-stripe each) + PERMUTED coalesced store: within each 128-col block,
// position p = lr*8 + ks holds key kcol = ks*16+lr. Each lane stores 8
// contiguous u16 (dwordx4) instead of 64 scalars. Per-wave live accumulator
// is only c8[8] (32 VGPR) -- viable at 512 threads (round-6 failure was the
// 4-wave version's c[2][8]). select_rows inverts the permutation at emit.
// ---------------------------------------------------------------------------
__global__ __launch_bounds__(512) void score_mfma(
    const unsigned short* __restrict__ Qhi, const unsigned short* __restrict__ Qlo,
    const unsigned short* __restrict__ Khi, const unsigned short* __restrict__ Klo,
    unsigned short* __restrict__ S16, int bh0)
{
  extern __shared__ unsigned short sm[];
  unsigned short* qh = sm;              // 128*72
  unsigned short* ql = qh + 128*72;
  unsigned short* kh = ql + 128*72;
  unsigned short* kl = kh + 128*72;     // total 73,728 B

  const int t  = threadIdx.x;
  const int qt = blockIdx.x, kt = blockIdx.y;
  const int bh = bh0 + blockIdx.z;
  const size_t qbase = ((size_t)bh*NQ + qt*128) * 64;
  const size_t kbase = ((size_t)bh*NK + kt*128) * 64;

  #pragma unroll
  for (int i = 0; i < 2; ++i) {
    int c   = t + i*512;
    int row = c >> 3, off = (c & 7) * 8;
    *(u16x8*)(qh + row*72 + off) = *(const u16x8*)(Qhi + qbase + row*64 + off);
    *(u16x8*)(ql + row*72 + off) = *(const u16x8*)(Qlo + qbase + row*64 + off);
    *(u16x8*)(kh + row*72 + off) = *(const u16x8*)(Khi + kbase + row*64 + off);
    *(u16x8*)(kl + row*72 + off) = *(const u16x8*)(Klo + kbase + row*64 + off);
  }
  __syncthreads();

  const int w = t >> 6, l = t & 63;
  const int quad = l >> 4, lr = l & 15;

  frag_ab aH[2], aL[2];
  {
    int row = w*16 + lr;
    #pragma unroll
    for (int s = 0; s < 2; ++s) {
      aH[s] = *(const frag_ab*)(qh + row*72 + s*32 + quad*8);
      aL[s] = *(const frag_ab*)(ql + row*72 + s*32 + quad*8);
    }
  }

  frag_cd c8[8];
  #pragma unroll
  for (int ks = 0; ks < 8; ++ks) {
    frag_ab bH[2], bL[2];
    int krow = ks*16 + lr;
    #pragma unroll
    for (int s = 0; s < 2; ++s) {
      bH[s] = *(const frag_ab*)(kh + krow*72 + s*32 + quad*8);
      bL[s] = *(const frag_ab*)(kl + krow*72 + s*32 + quad*8);
    }
    frag_cd c = {0.f, 0.f, 0.f, 0.f};
    #pragma unroll
    for (int s = 0; s < 2; ++s) {
      c = __builtin_amdgcn_mfma_f32_16x16x32_bf16(aH[s], bH[s], c, 0, 0, 0);
      c = __builtin_amdgcn_mfma_f32_16x16x32_bf16(aH[s], bL[s], c, 0, 0, 0);
      c = __builtin_amdgcn_mfma_f32_16x16x32_bf16(aL[s], bH[s], c, 0, 0, 0);
    }
    c8[ks] = c;
  }

  // permuted coalesced store: 8 contiguous u16 per i at p = lr*8 + ks
  #pragma unroll
  for (int i = 0; i < 4; ++i) {
    unsigned short o8[8];
    #pragma unroll
    for (int ks = 0; ks < 8; ++ks) {
      _Float16 h = (_Float16)(c8[ks][i] * 0.125f);
      o8[ks] = __builtin_bit_cast(unsigned short, h);
    }
    int qrow = qt*128 + w*16 + quad*4 + i;
    size_t base = ((size_t)blockIdx.z * NQ + qrow) * NK + kt*128 + lr*8;
    *(u16x8*)(S16 + base) = *(u16x8*)o8;
  }
}

// ---------------------------------------------------------------------------
// Select: exact f16-bits kth via binary search, margin collect (skth - 3e-3).
// Round-5 compute structure (scalar loads, uv[] register-resident); only
// delta: emit-time inversion of score's permuted column layout:
//   key = (p & ~127) | ((p&7)<<4) | ((p>>3)&15)   with p = c*64 + l.
// (validated round 7: neutral perf, identical absmax)
// ---------------------------------------------------------------------------
__global__ __launch_bounds__(256) void select_rows(
    const unsigned short* __restrict__ S16, unsigned short* __restrict__ cand,
    int* __restrict__ cnt, const int* __restrict__ topkp, int row0)
{
  const int t = threadIdx.x;
  const int w = t >> 6, l = t & 63;
  const int rl = blockIdx.x * 4 + w;
  const size_t row = (size_t)row0 + rl;
  const unsigned short* Sr = S16 + (size_t)rl * NK;
  const unsigned long long lmask = (1ull << l) - 1ull;

  int kEff = *topkp;
  if (kEff > CAND_MAX) kEff = CAND_MAX;
  if (kEff < 1) kEff = 1;

  unsigned uv[32];
  #pragma unroll
  for (int c = 0; c < 32; ++c) {
    unsigned bb = Sr[c*64 + l];
    uv[c] = (bb & 0x8000u) ? (~bb & 0xFFFFu) : (bb | 0x8000u);
  }
  unsigned lo_ = 0u, hi_ = 0xFFFFu;
  while (lo_ < hi_) {
    unsigned mid = (lo_ + hi_ + 1u) >> 1;
    int c_ = 0;
    #pragma unroll
    for (int c = 0; c < 32; ++c) c_ += (uv[c] >= mid) ? 1 : 0;
    #pragma unroll
    for (int off = 32; off > 0; off >>= 1) c_ += __shfl_xor(c_, off);
    if (c_ >= kEff) lo_ = mid; else hi_ = mid - 1;
  }
  unsigned short sb = (lo_ & 0x8000u) ? (unsigned short)(lo_ & 0x7FFFu)
                                      : (unsigned short)(~lo_ & 0xFFFFu);
  float skth = (float)__builtin_bit_cast(_Float16, sb);
  float smarg = skth - 3e-3f;
  _Float16 hm = (_Float16)smarg;
  unsigned short mb = __builtin_bit_cast(unsigned short, hm);
  unsigned um = (mb & 0x8000u) ? (~(unsigned)mb & 0xFFFFu) : ((unsigned)mb | 0x8000u);

  int base = 0;
  for (int c = 0; c < 32; ++c) {
    bool pred = (uv[c] >= um);
    unsigned long long msk = __ballot(pred);
    if (pred) {
      int pos = base + __popcll(msk & lmask);
      if (pos < CAND_MAX) {
        unsigned p = (unsigned)c * 64u + (unsigned)l;
        unsigned key = (p & 0xFF80u) | ((p & 7u) << 4) | ((p >> 3) & 15u);
        cand[row*CAND_MAX + pos] = (unsigned short)key;
      }
    }
    base += __popcll(msk);
  }
  if (l == 0) cnt[row] = (base < CAND_MAX) ? base : CAND_MAX;
}

// ---------------------------------------------------------------------------
// Phase B: group-coalesced rescore (8 cand/pass, float2 loads, exact f64
// accumulation -- round-8 proven form), two-level exact u64 kth, delta-blend,
// LDS-staged 16-lane x float4 PV, write inner. XCD-chunked block swizzle.
// ---------------------------------------------------------------------------
__global__ __launch_bounds__(256) void attn_phase_b(
    const float* __restrict__ Q32, const float* __restrict__ K32,
    const float* __restrict__ V32, const unsigned short* __restrict__ cand,
    const int* __restrict__ cnt, float* __restrict__ inner,
    const int* __restrict__ topkp)
{
  __shared__ uint2 pvbuf[4][128];   // per-wave (key, weight) pairs, 4 KB

  const int t = threadIdx.x;
  const int w = t >> 6, l = t & 63;
  // XCD-chunked swizzle: grid 16384 = 8 XCDs x 2048 contiguous blocks.
  const int nwg = (int)gridDim.x;             // 16384, divisible by 8
  const int bid = (int)blockIdx.x;
  const int swz = (bid & 7) * (nwg >> 3) + (bid >> 3);
  const size_t row = (size_t)swz * 4 + w;
  const int bh = (int)(row >> 11);
  const int q  = (int)(row & (NQ - 1));
  const unsigned long long lmask = (1ull << l) - 1ull;

  int kEff = *topkp;
  if (kEff > CAND_MAX) kEff = CAND_MAX;
  if (kEff < 1) kEff = 1;
  int m = cnt[row];
  if (kEff > m) kEff = m;

  const float* Kb = K32 + (size_t)bh * NK * 64;
  const float* Vb = V32 + (size_t)bh * NK * 64;

  const int g = l >> 3, r = l & 7;
  // Q values are exact f32; widen once to f64 registers (cvt is exact).
  double2 q2[4];
  #pragma unroll
  for (int i = 0; i < 4; ++i) {
    float2 qf = *(const float2*)(Q32 + row*64 + i*16 + r*2);
    q2[i].x = (double)qf.x;
    q2[i].y = (double)qf.y;
  }

  int ck[2];
  ck[0] = cand[row*CAND_MAX + l];
  ck[1] = cand[row*CAND_MAX + 64 + l];
  double cs[2] = {-INFINITY, -INFINITY};
  unsigned long long cu[2] = {0ull, 0ull};

  #define RESCORE_PASS(P, C)                                                  \
  {                                                                           \
    const int j = (P)*8 + g;                                                  \
    const bool valid = (j < m);                                               \
    int key = __shfl(ck[C], j & 63);                                          \
    const float* kp = Kb + (size_t)(valid ? key : 0) * 64;                    \
    double s0 = 0.0, s1 = 0.0;                                                \
    _Pragma("unroll")                                                         \
    for (int i = 0; i < 4; ++i) {                                             \
      float2 kv = *(const float2*)(kp + i*16 + r*2);                          \
      s0 = fma((double)kv.x, q2[i].x, s0);                                    \
      s1 = fma((double)kv.y, q2[i].y, s1);                                    \
    }                                                                         \
    double s = s0 + s1;                                                       \
    s += __shfl_xor(s, 1);                                                    \
    s += __shfl_xor(s, 2);                                                    \
    s += __shfl_xor(s, 4);                                                    \
    s *= 0.125;                                                               \
    double sc = __shfl(s, (l & 7) * 8);                                       \
    const int pp = (P) & 7;                                                   \
    if ((l >> 3) == pp && ((C)*64 + pp*8 + (l & 7)) < m) {                    \
      unsigned long long b = (unsigned long long)__double_as_longlong(sc);    \
      cs[C] = sc;                                                             \
      cu[C] = (b >> 63) ? ~b : (b | 0x8000000000000000ull);                   \
    }                                                                         \
  }

  if (m <= 64) {
    #pragma unroll
    for (int p = 0; p < 8; ++p) RESCORE_PASS(p, 0)
  } else {
    #pragma unroll
    for (int p = 0; p < 8; ++p) RESCORE_PASS(p, 0)
    // dynamic second batch: only as many passes as candidates require
    const int np2 = 8 + ((m - 64 + 7) >> 3);
    for (int p = 8; p < np2; ++p) RESCORE_PASS(p, 1)
  }
  #undef RESCORE_PASS

  // ---- exact 64-bit kth via two-level radix: hi32 search, lo32 on ties ----
  const unsigned hu0 = (unsigned)(cu[0] >> 32), lu0 = (unsigned)cu[0];
  const unsigned hu1 = (unsigned)(cu[1] >> 32), lu1 = (unsigned)cu[1];

  unsigned T32 = 0u;
  for (int bit = 31; bit >= 0; --bit) {
    unsigned cT = T32 | (1u << bit);
    int tot = __popcll(__ballot(hu0 >= cT)) + __popcll(__ballot(hu1 >= cT));
    if (tot >= kEff) T32 = cT;
  }
  unsigned Tlo;
  {
    int cgt32 = __popcll(__ballot(hu0 > T32)) + __popcll(__ballot(hu1 > T32));
    bool e0 = (hu0 == T32), e1 = (hu1 == T32);
    unsigned long long bm0 = __ballot(e0), bm1 = __ballot(e1);
    int ceq = __popcll(bm0) + __popcll(bm1);
    int nEq32 = kEff - cgt32;              // in [1, ceq]
    if (ceq == 1) {
      // single hi32 match (overwhelmingly common): fetch its low word
      Tlo = bm0 ? __shfl(lu0, (int)__builtin_ctzll(bm0))
                : __shfl(lu1, (int)__builtin_ctzll(bm1));
    } else {
      unsigned TL = 0u;
      for (int bit = 31; bit >= 0; --bit) {
        unsigned cT = TL | (1u << bit);
        int tot = __popcll(__ballot(e0 && lu0 >= cT))
                + __popcll(__ballot(e1 && lu1 >= cT));
        if (tot >= nEq32) TL = cT;
      }
      Tlo = TL;
    }
  }
  const unsigned long long T = ((unsigned long long)T32 << 32) | Tlo;

  double s_kth;
  { unsigned long long bb = (T >> 63) ? (T & 0x7FFFFFFFFFFFFFFFull) : ~T;
    s_kth = __longlong_as_double((long long)bb); }

  double nx = -INFINITY;
  #pragma unroll
  for (int c = 0; c < 2; ++c) { double v = (cu[c] < T) ? cs[c] : -INFINITY; nx = fmax(nx, v); }
  #pragma unroll
  for (int off = 32; off > 0; off >>= 1) nx = fmax(nx, __shfl_xor(nx, off));

  double smax = fmax(cs[0], cs[1]);
  #pragma unroll
  for (int off = 32; off > 0; off >>= 1) smax = fmax(smax, __shfl_xor(smax, off));

  const double DELTA = 5e-6;
  float wgt[2];
  if (!(s_kth - nx < 2.0*DELTA)) {
    int cgt = __popcll(__ballot(cu[0] > T)) + __popcll(__ballot(cu[1] > T));
    int nEq = kEff - cgt;
    int eqBase = 0;
    #pragma unroll
    for (int c = 0; c < 2; ++c) {
      bool eq = (cu[c] == T);
      unsigned long long eqm = __ballot(eq);
      int er = __popcll(eqm & lmask);
      bool sel = (cu[c] > T) || (eq && (eqBase + er) < nEq);
      eqBase += __popcll(eqm);
      wgt[c] = sel ? expf((float)(cs[c] - smax)) : 0.f;
    }
  } else {
    double cmid = 0.5 * (s_kth + nx);
    #pragma unroll
    for (int c = 0; c < 2; ++c) {
      double mu = 0.5 + (cs[c] - cmid) / (2.0*DELTA);
      mu = fmin(1.0, fmax(0.0, mu));
      wgt[c] = (float)mu * expf((float)(cs[c] - smax));
    }
  }

  // ---- stash (key, weight) in per-wave LDS; wsum via wave reduce ----
  pvbuf[w][l]      = make_uint2((unsigned)ck[0] & (NK - 1), __float_as_uint(wgt[0]));
  pvbuf[w][64 + l] = make_uint2((unsigned)ck[1] & (NK - 1), __float_as_uint(wgt[1]));
  float wsum = wgt[0] + wgt[1];
  #pragma unroll
  for (int off = 32; off > 0; off >>= 1) wsum += __shfl_xor(wsum, off);
  asm volatile("s_waitcnt lgkmcnt(0)" ::: "memory");  // per-wave LDS ready

  // ---- PV: 16-lane x float4 layout; 4 candidates per iteration ----
  const int sub = l >> 4;          // candidate slot within group-of-4
  const int dl  = l & 15;          // dim quad: handles d = dl*4 .. dl*4+3
  const float* Vb4 = Vb + dl * 4;
  float ax = 0.f, ay = 0.f, az = 0.f, aw = 0.f;
  const int mm4 = (m + 3) & ~3;
  #pragma unroll 4
  for (int j0 = 0; j0 < mm4; j0 += 4) {
    uint2 p = pvbuf[w][j0 + sub];          // broadcast ds_read_b64, conflict-free
    float wj = __uint_as_float(p.y);
    const float4 v = *(const float4*)(Vb4 + ((size_t)p.x << 6));
    ax = fmaf(wj, v.x, ax);
    ay = fmaf(wj, v.y, ay);
    az = fmaf(wj, v.z, az);
    aw = fmaf(wj, v.w, aw);
  }
  // reduce across the 4 sub-groups
  #pragma unroll
  for (int off = 32; off >= 16; off >>= 1) {
    ax += __shfl_xor(ax, off);
    ay += __shfl_xor(ay, off);
    az += __shfl_xor(az, off);
    aw += __shfl_xor(aw, off);
  }
  if (sub == 0) {
    int b = bh >> 3, h = bh & 7;
    float inv = 1.0f / wsum;
    float4 o;
    o.x = ax * inv; o.y = ay * inv; o.z = az * inv; o.w = aw * inv;
    *(float4*)(inner + ((size_t)b*NQ + q)*INNER + h*DHEAD + dl*4) = o;
  }
}

// ---------------------------------------------------------------------------
extern "C" void kernel_launch(void* const* d_in, const int* in_sizes, int n_in,
                              void* d_out, int out_size, void* d_ws, size_t ws_size,
                              hipStream_t stream)
{
  const float* x    = (const float*)d_in[0];
  const float* ctx  = (const float*)d_in[1];
  const float* Wq   = (const float*)d_in[2];
  const float* Wkv  = (const float*)d_in[3];
  const float* Wout = (const float*)d_in[4];
  const float* bout = (const float*)d_in[5];
  const int*   topk = (const int*)d_in[6];
  float* out = (float*)d_out;

  const size_t SZ = (size_t)BATCH * NHEADS * NQ * DHEAD;  // 4,194,304

  // ---- fixed ws region (~80.5 MB) ----
  size_t off = 0;
  char* base = (char*)d_ws;
  auto take = [&](size_t bytes) { char* r = base + off; off += (bytes + 255) & ~(size_t)255; return r; };
  float* Q32 = (float*)take(SZ * sizeof(float));                           // 16 MB
  float* K32 = (float*)take(SZ * sizeof(float));                           // 16 MB
  unsigned short* cand = (unsigned short*)take((size_t)NROWS * CAND_MAX * 2); // 16 MB
  int* cnt = (int*)take((size_t)NROWS * sizeof(int));                      // 256 KB
  unsigned short* Qhi = (unsigned short*)take(SZ * 2);                     // 8 MB
  unsigned short* Qlo = (unsigned short*)take(SZ * 2);                     // 8 MB
  unsigned short* Khi = (unsigned short*)take(SZ * 2);                     // 8 MB
  unsigned short* Klo = (unsigned short*)take(SZ * 2);                     // 8 MB
  char* slab = base + off;   // remainder: time-multiplexed region

  // slab phase 1 (before/during projections): Wq/Wk 3-way splits (6 MB)
  const size_t WSZ = (size_t)INNER * DQ * 2;   // 1 MB per split array
  unsigned short* WqTH = (unsigned short*)(slab + 0*WSZ);
  unsigned short* WqTM = (unsigned short*)(slab + 1*WSZ);
  unsigned short* WqTL = (unsigned short*)(slab + 2*WSZ);
  unsigned short* WkTH = (unsigned short*)(slab + 3*WSZ);
  unsigned short* WkTM = (unsigned short*)(slab + 4*WSZ);
  unsigned short* WkTL = (unsigned short*)(slab + 5*WSZ);
  // slab phase 2 (score/select): f16 score chunks
  unsigned short* S16 = (unsigned short*)slab;
  // slab phase 3 (after select): Wv/Wo 2-way splits (4 MB)
  unsigned short* WvTH = (unsigned short*)(slab + 0*WSZ);
  unsigned short* WvTL = (unsigned short*)(slab + 1*WSZ);
  unsigned short* WoTH = (unsigned short*)(slab + 2*WSZ);
  unsigned short* WoTL = (unsigned short*)(slab + 3*WSZ);
  // Aliases over fixed region (dead after score/select):
  float* V32   = (float*)Qhi;               // 16 MB over Qhi+Qlo
  float* inner = (float*)Khi;               // 16 MB over Khi+Klo

  const size_t per_bh = (size_t)NQ * NK * sizeof(unsigned short);  // 8 MB
  size_t avail = (ws_size > off) ? (ws_size - off) : 0;
  int bhchunk = (int)(avail / per_bh);
  if (bhchunk < 1)  bhchunk = 1;
  if (bhchunk > 32) bhchunk = 32;

  const int M = BATCH * NQ;  // 8192
  const int SCORE_LDS = 4 * 128 * 72 * (int)sizeof(unsigned short); // 73,728 B
  const int PROJ_LDS  = 6 * 128 * 40 * (int)sizeof(unsigned short); // 61,440 B
  hipFuncSetAttribute(reinterpret_cast<const void*>(score_mfma),
                      hipFuncAttributeMaxDynamicSharedMemorySize, SCORE_LDS);
  hipFuncSetAttribute(reinterpret_cast<const void*>(gemm_mfma6_proj),
                      hipFuncAttributeMaxDynamicSharedMemorySize, PROJ_LDS);

  // Wq / Wk(first half of Wkv) transpose + 3-way split
  split_wT3<<<dim3(DQ/32, INNER/32), 256, 0, stream>>>(Wq,  INNER,   0, DQ, INNER, WqTH, WqTM, WqTL);
  split_wT3<<<dim3(DQ/32, INNER/32), 256, 0, stream>>>(Wkv, 2*INNER, 0, DQ, INNER, WkTH, WkTM, WkTL);

  // merged x+ctx projection: grid 512 (two 256-block halves, 128x128 tiles)
  gemm_mfma6_proj<<<dim3(512), 512, PROJ_LDS, stream>>>(
      x,   WqTH, WqTM, WqTL, Q32, Qhi, Qlo,
      ctx, WkTH, WkTM, WkTL, K32, Khi, Klo);

  for (int c0 = 0; c0 < BATCH*NHEADS; c0 += bhchunk) {
    int cc = BATCH*NHEADS - c0; if (cc > bhchunk) cc = bhchunk;
    score_mfma<<<dim3(NQ/128, NK/128, cc), 512, SCORE_LDS, stream>>>(
        Qhi, Qlo, Khi, Klo, S16, c0);
    select_rows<<<dim3(cc*NQ/4), 256, 0, stream>>>(S16, cand, cnt, topk, c0*NQ);
  }

  // slab phase 3: Wv/Wo splits (S16 dead after last select)
  split_wT<<<dim3(DQ/32, INNER/32), 256, 0, stream>>>(Wkv, 2*INNER, INNER, DQ, INNER, WvTH, WvTL);
  split_wT<<<dim3(INNER/32, DQ/32), 256, 0, stream>>>(Wout, DQ, 0, INNER, DQ, WoTH, WoTL);

  // V32 overwrites Qhi/Qlo (dead), inner overwrites Khi/Klo (dead).
  gemm_mfma3<2><<<dim3((INNER/128)*(M/128)), 512, 0, stream>>>(ctx, DQ, WvTH, WvTL, DQ, INNER, nullptr, V32);
  attn_phase_b<<<dim3(NROWS/4), 256, 0, stream>>>(Q32, K32, V32, cand, cnt, inner, topk);
  gemm_mfma3<0><<<dim3((DQ/128)*(M/128)), 512, 0, stream>>>(inner, INNER, WoTH, WoTL, INNER, DQ, bout, out);
}

// Round 13
// 688.737 us; speedup vs baseline: 1.0253x; 1.0253x over previous
//
#include <hip/hip_runtime.h>
#include <math.h>

#define BATCH 4
#define NQ 2048
#define NK 2048
#define DQ 1024
#define NHEADS 8
#define DHEAD 64
#define INNER (NHEADS*DHEAD)     // 512
#define NROWS (BATCH*NHEADS*NQ)  // 65536
#define CAND_MAX 128

using frag_ab = __attribute__((ext_vector_type(8))) short;   // 8 bf16
using frag_cd = __attribute__((ext_vector_type(4))) float;   // 4 fp32
using u16x8   = __attribute__((ext_vector_type(8))) unsigned short;

static __device__ __forceinline__ unsigned short f32_to_bf16_rne(float f) {
  unsigned u = __float_as_uint(f);
  u += 0x7FFFu + ((u >> 16) & 1u);
  return (unsigned short)(u >> 16);
}

// 2-way trunc split (for smooth-path mfma3): f ~ hi + lo, err ~2^-17|f|
static __device__ __forceinline__ void split_trunc(float f, unsigned short& h, unsigned short& l) {
  unsigned u = __float_as_uint(f);
  h = (unsigned short)(u >> 16);
  float hf = __uint_as_float(u & 0xFFFF0000u);
  unsigned r = __float_as_uint(f - hf);
  l = (unsigned short)(r >> 16);
}

// 3-way trunc split: f = hi + mid + lo EXACTLY (8+8+8 mantissa bits)
static __device__ __forceinline__ void split3(float f, unsigned short& h,
                                              unsigned short& m, unsigned short& l) {
  unsigned u = __float_as_uint(f);
  h = (unsigned short)(u >> 16);
  float hf = __uint_as_float(u & 0xFFFF0000u);
  float r1 = f - hf;                       // exact
  unsigned u1 = __float_as_uint(r1);
  m = (unsigned short)(u1 >> 16);
  float mf = __uint_as_float(u1 & 0xFFFF0000u);
  float r2 = r1 - mf;                      // exact, <=8 mantissa bits
  l = (unsigned short)(__float_as_uint(r2) >> 16);
}

// ---------------------------------------------------------------------------
// Weight transpose + 3-way split: W[K][ldw] (coloff) -> TH/TM/TL [N][K] u16.
// ---------------------------------------------------------------------------
__global__ __launch_bounds__(256) void split_wT3(
    const float* __restrict__ W, int ldw, int coloff, int K, int N,
    unsigned short* __restrict__ TH, unsigned short* __restrict__ TM,
    unsigned short* __restrict__ TL)
{
  __shared__ float tile[32*33];
  const int k0 = blockIdx.x * 32, n0 = blockIdx.y * 32;
  const int t = threadIdx.x;
  {
    int lk = t >> 3, ln4 = (t & 7) * 4;
    const float4 v = *(const float4*)(W + (size_t)(k0 + lk)*ldw + coloff + n0 + ln4);
    tile[lk*33 + ln4+0] = v.x;
    tile[lk*33 + ln4+1] = v.y;
    tile[lk*33 + ln4+2] = v.z;
    tile[lk*33 + ln4+3] = v.w;
  }
  __syncthreads();
  int n = t >> 3, k4 = (t & 7) * 4;
  #pragma unroll
  for (int j = 0; j < 4; ++j) {
    unsigned short h, m, l;
    split3(tile[(k4+j)*33 + n], h, m, l);
    size_t o = (size_t)(n0 + n)*K + k0 + k4 + j;
    TH[o] = h; TM[o] = m; TL[o] = l;
  }
}

// ---------------------------------------------------------------------------
// Weight transpose + 2-way split (smooth path).
// ---------------------------------------------------------------------------
__global__ __launch_bounds__(256) void split_wT(
    const float* __restrict__ W, int ldw, int coloff, int K, int N,
    unsigned short* __restrict__ TH, unsigned short* __restrict__ TL)
{
  __shared__ float tile[32*33];
  const int k0 = blockIdx.x * 32, n0 = blockIdx.y * 32;
  const int t = threadIdx.x;
  {
    int lk = t >> 3, ln4 = (t & 7) * 4;
    const float4 v = *(const float4*)(W + (size_t)(k0 + lk)*ldw + coloff + n0 + ln4);
    tile[lk*33 + ln4+0] = v.x;
    tile[lk*33 + ln4+1] = v.y;
    tile[lk*33 + ln4+2] = v.z;
    tile[lk*33 + ln4+3] = v.w;
  }
  __syncthreads();
  int n = t >> 3, k4 = (t & 7) * 4;
  #pragma unroll
  for (int j = 0; j < 4; ++j) {
    unsigned short h, l;
    split_trunc(tile[(k4+j)*33 + n], h, l);
    TH[(size_t)(n0 + n)*K + k0 + k4 + j] = h;
    TL[(size_t)(n0 + n)*K + k0 + k4 + j] = l;
  }
}

// ---------------------------------------------------------------------------
// 6-product bf16 MFMA projection GEMM (selection path, ~1e-6 abs err):
// MERGED x+ctx launch. Tile 128m x 128n, BK=32, 8 waves (512 thr),
// 61,440 B LDS -> 2 blocks/CU, grid 512 = exact fill.
// ---------------------------------------------------------------------------
__global__ __launch_bounds__(512) void gemm_mfma6_proj(
    const float* __restrict__ A0,
    const unsigned short* __restrict__ BtH0, const unsigned short* __restrict__ BtM0,
    const unsigned short* __restrict__ BtL0,
    float* __restrict__ C0_, unsigned short* __restrict__ Hi0, unsigned short* __restrict__ Lo0,
    const float* __restrict__ A1,
    const unsigned short* __restrict__ BtH1, const unsigned short* __restrict__ BtM1,
    const unsigned short* __restrict__ BtL1,
    float* __restrict__ C1_, unsigned short* __restrict__ Hi1, unsigned short* __restrict__ Lo1)
{
  extern __shared__ unsigned short smp[];
  unsigned short* ah = smp;            // [128][40] u16 each (rows 16B-aligned)
  unsigned short* am = ah + 128*40;
  unsigned short* al = am + 128*40;
  unsigned short* bh = al + 128*40;    // [128][40]
  unsigned short* bm = bh + 128*40;
  unsigned short* bl = bm + 128*40;    // total 61,440 B

  const int t = threadIdx.x;
  const int w = t >> 6, l = t & 63;
  const int lr = l & 15, quad = l >> 4;
  const int bid = (int)blockIdx.x;                  // grid 512
  const int half = bid >> 8;                        // 0: x-proj, 1: ctx-proj
  const int b2 = bid & 255;
  const int lid = (b2 & 7) * 32 + (b2 >> 3);        // per-half XCD chunking
  const int n0 = (lid & 3) * 128, m0 = (lid >> 2) * 128;

  const float* A = half ? A1 : A0;
  const unsigned short* BtH = half ? BtH1 : BtH0;
  const unsigned short* BtM = half ? BtM1 : BtM0;
  const unsigned short* BtL = half ? BtL1 : BtL0;
  float* C32 = half ? C1_ : C0_;
  unsigned short* Hi = half ? Hi1 : Hi0;
  unsigned short* Lo = half ? Lo1 : Lo0;

  frag_cd acc[8];
  #pragma unroll
  for (int nt = 0; nt < 8; ++nt)
    acc[nt] = (frag_cd){0.f, 0.f, 0.f, 0.f};

  for (int kt = 0; kt < DQ; kt += 32) {
    // stage A: 128x32 f32 -> 3-way split (one u16x8 triple per thread)
    {
      int row = t >> 2, k8 = (t & 3) * 8;
      const float* src = A + (size_t)(m0 + row) * DQ + kt + k8;
      float4 v0 = *(const float4*)(src);
      float4 v1 = *(const float4*)(src + 4);
      float vv[8] = {v0.x, v0.y, v0.z, v0.w, v1.x, v1.y, v1.z, v1.w};
      unsigned short h8[8], m8[8], l8[8];
      #pragma unroll
      for (int j = 0; j < 8; ++j) split3(vv[j], h8[j], m8[j], l8[j]);
      *(u16x8*)(ah + row*40 + k8) = *(u16x8*)h8;
      *(u16x8*)(am + row*40 + k8) = *(u16x8*)m8;
      *(u16x8*)(al + row*40 + k8) = *(u16x8*)l8;
    }
    // stage B: 128x32 pre-split copies (one u16x8 triple per thread)
    {
      int n = t >> 2, k8 = (t & 3) * 8;
      size_t o = (size_t)(n0 + n)*DQ + kt + k8;
      *(u16x8*)(bh + n*40 + k8) = *(const u16x8*)(BtH + o);
      *(u16x8*)(bm + n*40 + k8) = *(const u16x8*)(BtM + o);
      *(u16x8*)(bl + n*40 + k8) = *(const u16x8*)(BtL + o);
    }
    __syncthreads();
    {
      int row = w*16 + lr;
      frag_ab aH = *(const frag_ab*)(ah + row*40 + quad*8);
      frag_ab aM = *(const frag_ab*)(am + row*40 + quad*8);
      frag_ab aL = *(const frag_ab*)(al + row*40 + quad*8);
      #pragma unroll
      for (int nt = 0; nt < 8; ++nt) {
        int bn = nt*16 + lr;
        frag_ab bH_ = *(const frag_ab*)(bh + bn*40 + quad*8);
        frag_ab bM_ = *(const frag_ab*)(bm + bn*40 + quad*8);
        frag_ab bL_ = *(const frag_ab*)(bl + bn*40 + quad*8);
        frag_cd c = acc[nt];
        // small terms first to reduce rounding (order preserved)
        c = __builtin_amdgcn_mfma_f32_16x16x32_bf16(aL, bH_, c, 0, 0, 0);
        c = __builtin_amdgcn_mfma_f32_16x16x32_bf16(aH, bL_, c, 0, 0, 0);
        c = __builtin_amdgcn_mfma_f32_16x16x32_bf16(aM, bM_, c, 0, 0, 0);
        c = __builtin_amdgcn_mfma_f32_16x16x32_bf16(aM, bH_, c, 0, 0, 0);
        c = __builtin_amdgcn_mfma_f32_16x16x32_bf16(aH, bM_, c, 0, 0, 0);
        c = __builtin_amdgcn_mfma_f32_16x16x32_bf16(aH, bH_, c, 0, 0, 0);
        acc[nt] = c;
      }
    }
    __syncthreads();
  }

  #pragma unroll
  for (int nt = 0; nt < 8; ++nt) {
    int cc = n0 + nt*16 + lr;
    int h = cc >> 6, d = cc & 63;
    #pragma unroll
    for (int i = 0; i < 4; ++i) {
      int r = m0 + w*16 + quad*4 + i;
      int b = r >> 11, n = r & (NQ - 1);
      size_t idx = (((size_t)(b*NHEADS + h))*NQ + n)*64 + d;
      float vf = acc[nt][i];
      C32[idx] = vf;
      unsigned short hb = f32_to_bf16_rne(vf);
      float hf = __uint_as_float((unsigned)hb << 16);
      unsigned short lb = f32_to_bf16_rne(vf - hf);
      Hi[idx] = hb;
      Lo[idx] = lb;
    }
  }
}

// ---------------------------------------------------------------------------
// bf16x3 MFMA GEMM (smooth path). Tile 128m x 128n, BK=32, 8 waves (512 thr),
// 40,960 B LDS. 1D grid + chunked XCD swizzle.
// MODE 0: +bias row-major; MODE 2: scatter V[bh][n][d].
// ---------------------------------------------------------------------------
template<int MODE>
__global__ __launch_bounds__(512) void gemm_mfma3(
    const float* __restrict__ A, int lda,
    const unsigned short* __restrict__ BtH, const unsigned short* __restrict__ BtL,
    int K, int N, const float* __restrict__ bias, float* __restrict__ C0)
{
  __shared__ unsigned short ah[128*40];
  __shared__ unsigned short al[128*40];
  __shared__ unsigned short bh2[128*40];
  __shared__ unsigned short bl2[128*40];   // total 40,960 B
  const int t = threadIdx.x;
  const int w = t >> 6, l = t & 63;
  const int lr = l & 15, quad = l >> 4;
  const int nx = N >> 7;                       // 128-col n-blocks
  const int bid = (int)blockIdx.x;
  const int nwg = (int)gridDim.x;              // %8 == 0
  const int lid = (bid & 7) * (nwg >> 3) + (bid >> 3);
  const int n0 = (lid % nx) * 128, m0 = (lid / nx) * 128;

  frag_cd acc[8];
  #pragma unroll
  for (int nt = 0; nt < 8; ++nt)
    acc[nt] = (frag_cd){0.f, 0.f, 0.f, 0.f};

  for (int kt = 0; kt < K; kt += 32) {
    // stage A: 128x32 f32 -> 2-way split (one u16x8 pair per thread)
    {
      int row = t >> 2, k8 = (t & 3) * 8;
      const float* src = A + (size_t)(m0 + row) * lda + kt + k8;
      float4 v0 = *(const float4*)(src);
      float4 v1 = *(const float4*)(src + 4);
      float vv[8] = {v0.x, v0.y, v0.z, v0.w, v1.x, v1.y, v1.z, v1.w};
      unsigned short h8[8], l8[8];
      #pragma unroll
      for (int j = 0; j < 8; ++j) split_trunc(vv[j], h8[j], l8[j]);
      *(u16x8*)(ah + row*40 + k8) = *(u16x8*)h8;
      *(u16x8*)(al + row*40 + k8) = *(u16x8*)l8;
    }
    // stage B: 128x32 pre-split copies (one u16x8 pair per thread)
    {
      int n = t >> 2, k8 = (t & 3) * 8;
      size_t o = (size_t)(n0 + n)*K + kt + k8;
      *(u16x8*)(bh2 + n*40 + k8) = *(const u16x8*)(BtH + o);
      *(u16x8*)(bl2 + n*40 + k8) = *(const u16x8*)(BtL + o);
    }
    __syncthreads();
    {
      int row = w*16 + lr;
      frag_ab aH = *(const frag_ab*)(ah + row*40 + quad*8);
      frag_ab aL = *(const frag_ab*)(al + row*40 + quad*8);
      #pragma unroll
      for (int nt = 0; nt < 8; ++nt) {
        int bn = nt*16 + lr;
        frag_ab bH_ = *(const frag_ab*)(bh2 + bn*40 + quad*8);
        frag_ab bL_ = *(const frag_ab*)(bl2 + bn*40 + quad*8);
        acc[nt] = __builtin_amdgcn_mfma_f32_16x16x32_bf16(aH, bH_, acc[nt], 0, 0, 0);
        acc[nt] = __builtin_amdgcn_mfma_f32_16x16x32_bf16(aH, bL_, acc[nt], 0, 0, 0);
        acc[nt] = __builtin_amdgcn_mfma_f32_16x16x32_bf16(aL, bH_, acc[nt], 0, 0, 0);
      }
    }
    __syncthreads();
  }

  #pragma unroll
  for (int nt = 0; nt < 8; ++nt) {
    int cc = n0 + nt*16 + lr;
    #pragma unroll
    for (int i = 0; i < 4; ++i) {
      int r = m0 + w*16 + quad*4 + i;
      float v = acc[nt][i];
      if (MODE == 0) {
        C0[(size_t)r * N + cc] = v + bias[cc];
      } else {
        int b = r >> 11, n = r & (NQ - 1);
        int h = cc >> 6, d = cc & 63;
        C0[(((size_t)(b*NHEADS + h))*NK + n)*64 + d] = v;
      }
    }
  }
}

// ---------------------------------------------------------------------------
// Score GEMM via bf16x3 MFMA -> f16 scores. 512 threads: 8 waves each own a
// 16-row q-stripe; scalar per-ks stores (round-11 proven form -- permuted
// coalesced stores tested negative twice, rounds 6 and 12).
// ---------------------------------------------------------------------------
__global__ __launch_bounds__(512) void score_mfma(
    const unsigned short* __restrict__ Qhi, const unsigned short* __restrict__ Qlo,
    const unsigned short* __restrict__ Khi, const unsigned short* __restrict__ Klo,
    unsigned short* __restrict__ S16, int bh0)
{
  extern __shared__ unsigned short sm[];
  unsigned short* qh = sm;              // 128*72
  unsigned short* ql = qh + 128*72;
  unsigned short* kh = ql + 128*72;
  unsigned short* kl = kh + 128*72;     // total 73,728 B

  const int t  = threadIdx.x;
  const int qt = blockIdx.x, kt = blockIdx.y;
  const int bh = bh0 + blockIdx.z;
  const size_t qbase = ((size_t)bh*NQ + qt*128) * 64;
  const size_t kbase = ((size_t)bh*NK + kt*128) * 64;

  #pragma unroll
  for (int i = 0; i < 2; ++i) {
    int c   = t + i*512;
    int row = c >> 3, off = (c & 7) * 8;
    *(u16x8*)(qh + row*72 + off) = *(const u16x8*)(Qhi + qbase + row*64 + off);
    *(u16x8*)(ql + row*72 + off) = *(const u16x8*)(Qlo + qbase + row*64 + off);
    *(u16x8*)(kh + row*72 + off) = *(const u16x8*)(Khi + kbase + row*64 + off);
    *(u16x8*)(kl + row*72 + off) = *(const u16x8*)(Klo + kbase + row*64 + off);
  }
  __syncthreads();

  const int w = t >> 6, l = t & 63;
  const int quad = l >> 4, lr = l & 15;

  frag_ab aH[2], aL[2];
  {
    int row = w*16 + lr;
    #pragma unroll
    for (int s = 0; s < 2; ++s) {
      aH[s] = *(const frag_ab*)(qh + row*72 + s*32 + quad*8);
      aL[s] = *(const frag_ab*)(ql + row*72 + s*32 + quad*8);
    }
  }

  for (int ks = 0; ks < 8; ++ks) {
    frag_ab bH[2], bL[2];
    int krow = ks*16 + lr;
    #pragma unroll
    for (int s = 0; s < 2; ++s) {
      bH[s] = *(const frag_ab*)(kh + krow*72 + s*32 + quad*8);
      bL[s] = *(const frag_ab*)(kl + krow*72 + s*32 + quad*8);
    }
    frag_cd c = {0.f, 0.f, 0.f, 0.f};
    #pragma unroll
    for (int s = 0; s < 2; ++s) {
      c = __builtin_amdgcn_mfma_f32_16x16x32_bf16(aH[s], bH[s], c, 0, 0, 0);
      c = __builtin_amdgcn_mfma_f32_16x16x32_bf16(aH[s], bL[s], c, 0, 0, 0);
      c = __builtin_amdgcn_mfma_f32_16x16x32_bf16(aL[s], bH[s], c, 0, 0, 0);
    }
    int qrow = qt*128 + w*16 + quad*4;
    int kcol = kt*128 + ks*16 + lr;
    size_t base = ((size_t)blockIdx.z * NQ + qrow) * NK + kcol;
    #pragma unroll
    for (int i = 0; i < 4; ++i) {
      _Float16 h = (_Float16)(c[i] * 0.125f);
      S16[base + (size_t)i*NK] = __builtin_bit_cast(unsigned short, h);
    }
  }
}

// ---------------------------------------------------------------------------
// Select: exact f16-bits kth via binary search, margin collect (skth - 3e-3).
// Round-5 proven form (scalar loads, uv[] register-resident, direct keys).
// ---------------------------------------------------------------------------
__global__ __launch_bounds__(256) void select_rows(
    const unsigned short* __restrict__ S16, unsigned short* __restrict__ cand,
    int* __restrict__ cnt, const int* __restrict__ topkp, int row0)
{
  const int t = threadIdx.x;
  const int w = t >> 6, l = t & 63;
  const int rl = blockIdx.x * 4 + w;
  const size_t row = (size_t)row0 + rl;
  const unsigned short* Sr = S16 + (size_t)rl * NK;
  const unsigned long long lmask = (1ull << l) - 1ull;

  int kEff = *topkp;
  if (kEff > CAND_MAX) kEff = CAND_MAX;
  if (kEff < 1) kEff = 1;

  unsigned uv[32];
  #pragma unroll
  for (int c = 0; c < 32; ++c) {
    unsigned bb = Sr[c*64 + l];
    uv[c] = (bb & 0x8000u) ? (~bb & 0xFFFFu) : (bb | 0x8000u);
  }
  unsigned lo_ = 0u, hi_ = 0xFFFFu;
  while (lo_ < hi_) {
    unsigned mid = (lo_ + hi_ + 1u) >> 1;
    int c_ = 0;
    #pragma unroll
    for (int c = 0; c < 32; ++c) c_ += (uv[c] >= mid) ? 1 : 0;
    #pragma unroll
    for (int off = 32; off > 0; off >>= 1) c_ += __shfl_xor(c_, off);
    if (c_ >= kEff) lo_ = mid; else hi_ = mid - 1;
  }
  unsigned short sb = (lo_ & 0x8000u) ? (unsigned short)(lo_ & 0x7FFFu)
                                      : (unsigned short)(~lo_ & 0xFFFFu);
  float skth = (float)__builtin_bit_cast(_Float16, sb);
  float smarg = skth - 3e-3f;
  _Float16 hm = (_Float16)smarg;
  unsigned short mb = __builtin_bit_cast(unsigned short, hm);
  unsigned um = (mb & 0x8000u) ? (~(unsigned)mb & 0xFFFFu) : ((unsigned)mb | 0x8000u);

  int base = 0;
  for (int c = 0; c < 32; ++c) {
    bool pred = (uv[c] >= um);
    unsigned long long msk = __ballot(pred);
    if (pred) {
      int pos = base + __popcll(msk & lmask);
      if (pos < CAND_MAX) cand[row*CAND_MAX + pos] = (unsigned short)(c*64 + l);
    }
    base += __popcll(msk);
  }
  if (l == 0) cnt[row] = (base < CAND_MAX) ? base : CAND_MAX;
}

// ---------------------------------------------------------------------------
// Phase B: group-coalesced rescore (8 cand/pass, float2 loads, exact f64
// accumulation -- round-8 proven form), two-level exact u64 kth, delta-blend,
// LDS-staged 16-lane x float4 PV, write inner. XCD-chunked block swizzle.
// ---------------------------------------------------------------------------
__global__ __launch_bounds__(256) void attn_phase_b(
    const float* __restrict__ Q32, const float* __restrict__ K32,
    const float* __restrict__ V32, const unsigned short* __restrict__ cand,
    const int* __restrict__ cnt, float* __restrict__ inner,
    const int* __restrict__ topkp)
{
  __shared__ uint2 pvbuf[4][128];   // per-wave (key, weight) pairs, 4 KB

  const int t = threadIdx.x;
  const int w = t >> 6, l = t & 63;
  // XCD-chunked swizzle: grid 16384 = 8 XCDs x 2048 contiguous blocks.
  const int nwg = (int)gridDim.x;             // 16384, divisible by 8
  const int bid = (int)blockIdx.x;
  const int swz = (bid & 7) * (nwg >> 3) + (bid >> 3);
  const size_t row = (size_t)swz * 4 + w;
  const int bh = (int)(row >> 11);
  const int q  = (int)(row & (NQ - 1));
  const unsigned long long lmask = (1ull << l) - 1ull;

  int kEff = *topkp;
  if (kEff > CAND_MAX) kEff = CAND_MAX;
  if (kEff < 1) kEff = 1;
  int m = cnt[row];
  if (kEff > m) kEff = m;

  const float* Kb = K32 + (size_t)bh * NK * 64;
  const float* Vb = V32 + (size_t)bh * NK * 64;

  const int g = l >> 3, r = l & 7;
  // Q values are exact f32; widen once to f64 registers (cvt is exact).
  double2 q2[4];
  #pragma unroll
  for (int i = 0; i < 4; ++i) {
    float2 qf = *(const float2*)(Q32 + row*64 + i*16 + r*2);
    q2[i].x = (double)qf.x;
    q2[i].y = (double)qf.y;
  }

  int ck[2];
  ck[0] = cand[row*CAND_MAX + l];
  ck[1] = cand[row*CAND_MAX + 64 + l];
  double cs[2] = {-INFINITY, -INFINITY};
  unsigned long long cu[2] = {0ull, 0ull};

  #define RESCORE_PASS(P, C)                                                  \
  {                                                                           \
    const int j = (P)*8 + g;                                                  \
    const bool valid = (j < m);                                               \
    int key = __shfl(ck[C], j & 63);                                          \
    const float* kp = Kb + (size_t)(valid ? key : 0) * 64;                    \
    double s0 = 0.0, s1 = 0.0;                                                \
    _Pragma("unroll")                                                         \
    for (int i = 0; i < 4; ++i) {                                             \
      float2 kv = *(const float2*)(kp + i*16 + r*2);                          \
      s0 = fma((double)kv.x, q2[i].x, s0);                                    \
      s1 = fma((double)kv.y, q2[i].y, s1);                                    \
    }                                                                         \
    double s = s0 + s1;                                                       \
    s += __shfl_xor(s, 1);                                                    \
    s += __shfl_xor(s, 2);                                                    \
    s += __shfl_xor(s, 4);                                                    \
    s *= 0.125;                                                               \
    double sc = __shfl(s, (l & 7) * 8);                                       \
    const int pp = (P) & 7;                                                   \
    if ((l >> 3) == pp && ((C)*64 + pp*8 + (l & 7)) < m) {                    \
      unsigned long long b = (unsigned long long)__double_as_longlong(sc);    \
      cs[C] = sc;                                                             \
      cu[C] = (b >> 63) ? ~b : (b | 0x8000000000000000ull);                   \
    }                                                                         \
  }

  if (m <= 64) {
    #pragma unroll
    for (int p = 0; p < 8; ++p) RESCORE_PASS(p, 0)
  } else {
    #pragma unroll
    for (int p = 0; p < 8; ++p) RESCORE_PASS(p, 0)
    // dynamic second batch: only as many passes as candidates require
    const int np2 = 8 + ((m - 64 + 7) >> 3);
    for (int p = 8; p < np2; ++p) RESCORE_PASS(p, 1)
  }
  #undef RESCORE_PASS

  // ---- exact 64-bit kth via two-level radix: hi32 search, lo32 on ties ----
  const unsigned hu0 = (unsigned)(cu[0] >> 32), lu0 = (unsigned)cu[0];
  const unsigned hu1 = (unsigned)(cu[1] >> 32), lu1 = (unsigned)cu[1];

  unsigned T32 = 0u;
  for (int bit = 31; bit >= 0; --bit) {
    unsigned cT = T32 | (1u << bit);
    int tot = __popcll(__ballot(hu0 >= cT)) + __popcll(__ballot(hu1 >= cT));
    if (tot >= kEff) T32 = cT;
  }
  unsigned Tlo;
  {
    int cgt32 = __popcll(__ballot(hu0 > T32)) + __popcll(__ballot(hu1 > T32));
    bool e0 = (hu0 == T32), e1 = (hu1 == T32);
    unsigned long long bm0 = __ballot(e0), bm1 = __ballot(e1);
    int ceq = __popcll(bm0) + __popcll(bm1);
    int nEq32 = kEff - cgt32;              // in [1, ceq]
    if (ceq == 1) {
      // single hi32 match (overwhelmingly common): fetch its low word
      Tlo = bm0 ? __shfl(lu0, (int)__builtin_ctzll(bm0))
                : __shfl(lu1, (int)__builtin_ctzll(bm1));
    } else {
      unsigned TL = 0u;
      for (int bit = 31; bit >= 0; --bit) {
        unsigned cT = TL | (1u << bit);
        int tot = __popcll(__ballot(e0 && lu0 >= cT))
                + __popcll(__ballot(e1 && lu1 >= cT));
        if (tot >= nEq32) TL = cT;
      }
      Tlo = TL;
    }
  }
  const unsigned long long T = ((unsigned long long)T32 << 32) | Tlo;

  double s_kth;
  { unsigned long long bb = (T >> 63) ? (T & 0x7FFFFFFFFFFFFFFFull) : ~T;
    s_kth = __longlong_as_double((long long)bb); }

  double nx = -INFINITY;
  #pragma unroll
  for (int c = 0; c < 2; ++c) { double v = (cu[c] < T) ? cs[c] : -INFINITY; nx = fmax(nx, v); }
  #pragma unroll
  for (int off = 32; off > 0; off >>= 1) nx = fmax(nx, __shfl_xor(nx, off));

  double smax = fmax(cs[0], cs[1]);
  #pragma unroll
  for (int off = 32; off > 0; off >>= 1) smax = fmax(smax, __shfl_xor(smax, off));

  const double DELTA = 5e-6;
  float wgt[2];
  if (!(s_kth - nx < 2.0*DELTA)) {
    int cgt = __popcll(__ballot(cu[0] > T)) + __popcll(__ballot(cu[1] > T));
    int nEq = kEff - cgt;
    int eqBase = 0;
    #pragma unroll
    for (int c = 0; c < 2; ++c) {
      bool eq = (cu[c] == T);
      unsigned long long eqm = __ballot(eq);
      int er = __popcll(eqm & lmask);
      bool sel = (cu[c] > T) || (eq && (eqBase + er) < nEq);
      eqBase += __popcll(eqm);
      wgt[c] = sel ? expf((float)(cs[c] - smax)) : 0.f;
    }
  } else {
    double cmid = 0.5 * (s_kth + nx);
    #pragma unroll
    for (int c = 0; c < 2; ++c) {
      double mu = 0.5 + (cs[c] - cmid) / (2.0*DELTA);
      mu = fmin(1.0, fmax(0.0, mu));
      wgt[c] = (float)mu * expf((float)(cs[c] - smax));
    }
  }

  // ---- stash (key, weight) in per-wave LDS; wsum via wave reduce ----
  pvbuf[w][l]      = make_uint2((unsigned)ck[0] & (NK - 1), __float_as_uint(wgt[0]));
  pvbuf[w][64 + l] = make_uint2((unsigned)ck[1] & (NK - 1), __float_as_uint(wgt[1]));
  float wsum = wgt[0] + wgt[1];
  #pragma unroll
  for (int off = 32; off > 0; off >>= 1) wsum += __shfl_xor(wsum, off);
  asm volatile("s_waitcnt lgkmcnt(0)" ::: "memory");  // per-wave LDS ready

  // ---- PV: 16-lane x float4 layout; 4 candidates per iteration ----
  const int sub = l >> 4;          // candidate slot within group-of-4
  const int dl  = l & 15;          // dim quad: handles d = dl*4 .. dl*4+3
  const float* Vb4 = Vb + dl * 4;
  float ax = 0.f, ay = 0.f, az = 0.f, aw = 0.f;
  const int mm4 = (m + 3) & ~3;
  #pragma unroll 4
  for (int j0 = 0; j0 < mm4; j0 += 4) {
    uint2 p = pvbuf[w][j0 + sub];          // broadcast ds_read_b64, conflict-free
    float wj = __uint_as_float(p.y);
    const float4 v = *(const float4*)(Vb4 + ((size_t)p.x << 6));
    ax = fmaf(wj, v.x, ax);
    ay = fmaf(wj, v.y, ay);
    az = fmaf(wj, v.z, az);
    aw = fmaf(wj, v.w, aw);
  }
  // reduce across the 4 sub-groups
  #pragma unroll
  for (int off = 32; off >= 16; off >>= 1) {
    ax += __shfl_xor(ax, off);
    ay += __shfl_xor(ay, off);
    az += __shfl_xor(az, off);
    aw += __shfl_xor(aw, off);
  }
  if (sub == 0) {
    int b = bh >> 3, h = bh & 7;
    float inv = 1.0f / wsum;
    float4 o;
    o.x = ax * inv; o.y = ay * inv; o.z = az * inv; o.w = aw * inv;
    *(float4*)(inner + ((size_t)b*NQ + q)*INNER + h*DHEAD + dl*4) = o;
  }
}

// ---------------------------------------------------------------------------
extern "C" void kernel_launch(void* const* d_in, const int* in_sizes, int n_in,
                              void* d_out, int out_size, void* d_ws, size_t ws_size,
                              hipStream_t stream)
{
  const float* x    = (const float*)d_in[0];
  const float* ctx  = (const float*)d_in[1];
  const float* Wq   = (const float*)d_in[2];
  const float* Wkv  = (const float*)d_in[3];
  const float* Wout = (const float*)d_in[4];
  const float* bout = (const float*)d_in[5];
  const int*   topk = (const int*)d_in[6];
  float* out = (float*)d_out;

  const size_t SZ = (size_t)BATCH * NHEADS * NQ * DHEAD;  // 4,194,304

  // ---- fixed ws region (~80.5 MB) ----
  size_t off = 0;
  char* base = (char*)d_ws;
  auto take = [&](size_t bytes) { char* r = base + off; off += (bytes + 255) & ~(size_t)255; return r; };
  float* Q32 = (float*)take(SZ * sizeof(float));                           // 16 MB
  float* K32 = (float*)take(SZ * sizeof(float));                           // 16 MB
  unsigned short* cand = (unsigned short*)take((size_t)NROWS * CAND_MAX * 2); // 16 MB
  int* cnt = (int*)take((size_t)NROWS * sizeof(int));                      // 256 KB
  unsigned short* Qhi = (unsigned short*)take(SZ * 2);                     // 8 MB
  unsigned short* Qlo = (unsigned short*)take(SZ * 2);                     // 8 MB
  unsigned short* Khi = (unsigned short*)take(SZ * 2);                     // 8 MB
  unsigned short* Klo = (unsigned short*)take(SZ * 2);                     // 8 MB
  char* slab = base + off;   // remainder: time-multiplexed region

  // slab phase 1 (before/during projections): Wq/Wk 3-way splits (6 MB)
  const size_t WSZ = (size_t)INNER * DQ * 2;   // 1 MB per split array
  unsigned short* WqTH = (unsigned short*)(slab + 0*WSZ);
  unsigned short* WqTM = (unsigned short*)(slab + 1*WSZ);
  unsigned short* WqTL = (unsigned short*)(slab + 2*WSZ);
  unsigned short* WkTH = (unsigned short*)(slab + 3*WSZ);
  unsigned short* WkTM = (unsigned short*)(slab + 4*WSZ);
  unsigned short* WkTL = (unsigned short*)(slab + 5*WSZ);
  // slab phase 2 (score/select): f16 score chunks
  unsigned short* S16 = (unsigned short*)slab;
  // slab phase 3 (after select): Wv/Wo 2-way splits (4 MB)
  unsigned short* WvTH = (unsigned short*)(slab + 0*WSZ);
  unsigned short* WvTL = (unsigned short*)(slab + 1*WSZ);
  unsigned short* WoTH = (unsigned short*)(slab + 2*WSZ);
  unsigned short* WoTL = (unsigned short*)(slab + 3*WSZ);
  // Aliases over fixed region (dead after score/select):
  float* V32   = (float*)Qhi;               // 16 MB over Qhi+Qlo
  float* inner = (float*)Khi;               // 16 MB over Khi+Klo

  const size_t per_bh = (size_t)NQ * NK * sizeof(unsigned short);  // 8 MB
  size_t avail = (ws_size > off) ? (ws_size - off) : 0;
  int bhchunk = (int)(avail / per_bh);
  if (bhchunk < 1)  bhchunk = 1;
  if (bhchunk > 32) bhchunk = 32;

  const int M = BATCH * NQ;  // 8192
  const int SCORE_LDS = 4 * 128 * 72 * (int)sizeof(unsigned short); // 73,728 B
  const int PROJ_LDS  = 6 * 128 * 40 * (int)sizeof(unsigned short); // 61,440 B
  hipFuncSetAttribute(reinterpret_cast<const void*>(score_mfma),
                      hipFuncAttributeMaxDynamicSharedMemorySize, SCORE_LDS);
  hipFuncSetAttribute(reinterpret_cast<const void*>(gemm_mfma6_proj),
                      hipFuncAttributeMaxDynamicSharedMemorySize, PROJ_LDS);

  // Wq / Wk(first half of Wkv) transpose + 3-way split
  split_wT3<<<dim3(DQ/32, INNER/32), 256, 0, stream>>>(Wq,  INNER,   0, DQ, INNER, WqTH, WqTM, WqTL);
  split_wT3<<<dim3(DQ/32, INNER/32), 256, 0, stream>>>(Wkv, 2*INNER, 0, DQ, INNER, WkTH, WkTM, WkTL);

  // merged x+ctx projection: grid 512 (two 256-block halves, 128x128 tiles)
  gemm_mfma6_proj<<<dim3(512), 512, PROJ_LDS, stream>>>(
      x,   WqTH, WqTM, WqTL, Q32, Qhi, Qlo,
      ctx, WkTH, WkTM, WkTL, K32, Khi, Klo);

  for (int c0 = 0; c0 < BATCH*NHEADS; c0 += bhchunk) {
    int cc = BATCH*NHEADS - c0; if (cc > bhchunk) cc = bhchunk;
    score_mfma<<<dim3(NQ/128, NK/128, cc), 512, SCORE_LDS, stream>>>(
        Qhi, Qlo, Khi, Klo, S16, c0);
    select_rows<<<dim3(cc*NQ/4), 256, 0, stream>>>(S16, cand, cnt, topk, c0*NQ);
  }

  // slab phase 3: Wv/Wo splits (S16 dead after last select)
  split_wT<<<dim3(DQ/32, INNER/32), 256, 0, stream>>>(Wkv, 2*INNER, INNER, DQ, INNER, WvTH, WvTL);
  split_wT<<<dim3(INNER/32, DQ/32), 256, 0, stream>>>(Wout, DQ, 0, INNER, DQ, WoTH, WoTL);

  // V32 overwrites Qhi/Qlo (dead), inner overwrites Khi/Klo (dead).
  gemm_mfma3<2><<<dim3((INNER/128)*(M/128)), 512, 0, stream>>>(ctx, DQ, WvTH, WvTL, DQ, INNER, nullptr, V32);
  attn_phase_b<<<dim3(NROWS/4), 256, 0, stream>>>(Q32, K32, V32, cand, cnt, inner, topk);
  gemm_mfma3<0><<<dim3((DQ/128)*(M/128)), 512, 0, stream>>>(inner, INNER, WoTH, WoTL, INNER, DQ, bout, out);
}